// Round 5
// baseline (388.176 us; speedup 1.0000x reference)
//
#include <hip/hip_runtime.h>
#include <cstddef>

// Problem constants (fixed by reference setup)
constexpr int Bb   = 32;
constexpr int Ss   = 1024;
constexpr int Dd   = 256;
constexpr int Ff   = 256;
constexpr int TMAX = 8192;
constexpr int MM   = Bb * Ss;          // 32768 rows
constexpr int KK   = 768;              // 3*256 reduction dim
constexpr int SP   = 1026;             // padded seq len (zero rows at 0, 1025)
constexpr float LN_EPS = 1e-5f;
constexpr int PIT  = 72;               // LDS pitch (bf16): 144 B rows

constexpr int GEMM_BLK = MM / 64;      // 512 gemm blocks per launch
constexpr int GATH_TOT = Bb * TMAX * Dd / 4 / 256;  // 65536 gather blocks total
constexpr int GATH_HALF = GATH_TOT / 2;             // 32768 per gemm launch

typedef __bf16 bf16x8 __attribute__((ext_vector_type(8)));
typedef __bf16 bf16x4 __attribute__((ext_vector_type(4)));
typedef float  f32x4  __attribute__((ext_vector_type(4)));

// ---------------------------------------------------------------------------
// prep_k: three fused prep jobs, split by blockIdx.
//   [0,1536):    pack conv weights [F][D][K] fp32 -> [F][K*256+D] bf16
//   [1536,1568): per-batch cumsum + dur->float + mel_len + searchsorted
//   [1568,1584): zero xp2 pad rows (j=0 and j=1025)
// ---------------------------------------------------------------------------
__global__ __launch_bounds__(256) void prep_k(
    const float* __restrict__ w1, const float* __restrict__ w2,
    __bf16* __restrict__ wTT1, __bf16* __restrict__ wTT2,
    const int* __restrict__ dur, float* __restrict__ dur_out,
    float* __restrict__ mel_out, int* __restrict__ idx,
    __bf16* __restrict__ xp2)
{
    __shared__ int ic[1024];
    __shared__ int sc[256];
    const int blk = blockIdx.x;
    const int tid = threadIdx.x;

    if (blk < 1536) {                       // ---- pack weights ----
        int i = blk * 256 + tid;
        const float* w = w1;
        __bf16* o = wTT1;
        int j = i;
        if (j >= Ff * KK) { j -= Ff * KK; w = w2; o = wTT2; }
        int d  = j & 255;
        int fk = j >> 8;                    // f*3 + k
        int f  = fk / 3;
        int k  = fk - f * 3;
        o[(size_t)f * KK + k * 256 + d] = (__bf16)w[((size_t)(f * 256 + d)) * 3 + k];
        return;
    }
    if (blk >= 1568) {                      // ---- zero xp2 pad rows ----
        int j = (blk - 1568) * 256 + tid;   // 0..4095
        int b = j >> 7;
        int r = (j >> 6) & 1;
        int d = (j & 63) * 4;
        *(bf16x4*)&xp2[((size_t)b * SP + (size_t)r * (SP - 1)) * 256 + d] =
            (bf16x4)(__bf16)0.f;
        return;
    }
    // ---- cumsum + searchsorted for batch b ----
    int b = blk - 1536;
    int4 d4 = ((const int4*)(dur + b * 1024))[tid];
    int l0 = d4.x, l1 = l0 + d4.y, l2 = l1 + d4.z, l3 = l2 + d4.w;
    sc[tid] = l3;
    __syncthreads();
    for (int off = 1; off < 256; off <<= 1) {
        int v = (tid >= off) ? sc[tid - off] : 0;
        __syncthreads();
        sc[tid] += v;
        __syncthreads();
    }
    int excl = sc[tid] - l3;
    ((int4*)ic)[tid] = make_int4(excl + l0, excl + l1, excl + l2, excl + l3);
    ((float4*)(dur_out + b * 1024))[tid] =
        make_float4((float)d4.x, (float)d4.y, (float)d4.z, (float)d4.w);
    if (tid == 255) mel_out[b] = (float)min(excl + l3, TMAX);
    __syncthreads();
    int mel = min(ic[1023], TMAX);
    for (int t = tid; t < TMAX; t += 256) {
        int lo = 0, hi = 1024;
        #pragma unroll
        for (int it = 0; it < 10; ++it) {
            int mid = (lo + hi) >> 1;
            if (ic[mid] <= t) lo = mid + 1; else hi = mid;
        }
        idx[b * TMAX + t] = (t < mel) ? min(lo, 1023) : -1;
    }
}

// ---------------------------------------------------------------------------
// Fused conv-as-GEMM + bias + ReLU + LayerNorm [+ linear head], with HBM-bound
// gather blocks riding along in the same launch (blockIdx >= GEMM_BLK) to
// overlap the MFMA/LDS-bound gemm with the pure-HBM gather.
// Tile: BM=64 x BN=256 (full F), 256 threads / 4 waves, 64x64 per wave.
// MODE 0: A = fp32 x converted in staging; writes LN out bf16 to padded xp2;
//         gather half #0. MODE 1: A = xp2; writes log_dur fp32; gather half #1.
// ---------------------------------------------------------------------------
template<int MODE>
__global__ __launch_bounds__(256, 3) void gemm_fused(
    const float* __restrict__ Xf,    // [32][1024][256] fp32
    const __bf16* __restrict__ Ap,   // [32][1026][256] bf16 padded (MODE 1)
    const __bf16* __restrict__ Bw,   // [256][768]
    const float* __restrict__ bias,
    const float* __restrict__ g, const float* __restrict__ bt,
    const float* __restrict__ lw, const float* __restrict__ lb,
    const unsigned char* __restrict__ mask,
    __bf16* __restrict__ outB, float* __restrict__ outF,
    const int* __restrict__ idx, float4* __restrict__ outv)
{
    __shared__ __bf16 As[64 * PIT];    // 9216 B
    __shared__ __bf16 Bs[256 * PIT];   // 36864 B

    const int tid = threadIdx.x;

    if (blockIdx.x >= GEMM_BLK) {
        // ---- gather rider: one float4 per thread ----
        int gblk = blockIdx.x - GEMM_BLK + MODE * GATH_HALF;
        int gg   = gblk * 256 + tid;
        int row  = gg >> 6;                 // b*T + t
        int col  = gg & 63;
        int s = idx[row];
        float4 v = make_float4(0.f, 0.f, 0.f, 0.f);
        if (s >= 0) {
            int b = row >> 13;
            v = ((const float4*)Xf)[((size_t)(b << 10) + s) * 64 + col];
        }
        outv[gg] = v;
        return;
    }

    const int m0   = blockIdx.x * 64;
    const int bb   = m0 >> 10;
    const int s0   = m0 & 1023;
    const int wave = tid >> 6;
    const int lane = tid & 63;
    const int wn   = wave * 64;
    const int lm   = lane & 15;
    const int lk   = lane >> 4;

    f32x4 acc[4][4] = {};              // [mi][ni]

    for (int step = 0; step < KK / 64; ++step) {
        const int kk0  = step * 64;
        const int kblk = kk0 >> 8;     // conv tap
        const int d0   = kk0 & 255;

        // ---- stage A: 64 rows x 64 bf16 ----
        if constexpr (MODE == 0) {
            #pragma unroll
            for (int i = 0; i < 4; ++i) {
                int c = i * 256 + tid;          // 0..1023
                int r = c >> 4, q = c & 15;     // r:0..63, q:0..15
                int sg = s0 + r + kblk - 1;
                bf16x4 o = (bf16x4)(__bf16)0.f;
                if ((unsigned)sg < 1024u) {
                    float4 v = *(const float4*)&Xf[
                        (((size_t)(bb << 10) + sg) << 8) + d0 + q * 4];
                    o[0] = (__bf16)v.x; o[1] = (__bf16)v.y;
                    o[2] = (__bf16)v.z; o[3] = (__bf16)v.w;
                }
                *(bf16x4*)&As[r * PIT + q * 4] = o;
            }
        } else {
            const __bf16* aSrc = Ap + (((size_t)(bb * SP + s0 + kblk)) << 8) + d0;
            #pragma unroll
            for (int i = 0; i < 2; ++i) {
                int c = i * 256 + tid, r = c >> 3, q = c & 7;
                *(bf16x8*)&As[r * PIT + q * 8] =
                    *(const bf16x8*)&aSrc[((size_t)r << 8) + q * 8];
            }
        }
        // ---- stage B: 256 rows x 64 bf16 ----
        const __bf16* bSrc = Bw + kk0;
        #pragma unroll
        for (int i = 0; i < 8; ++i) {
            int c = i * 256 + tid, r = c >> 3, q = c & 7;
            *(bf16x8*)&Bs[r * PIT + q * 8] =
                *(const bf16x8*)&bSrc[(size_t)r * KK + q * 8];
        }
        __syncthreads();
        #pragma unroll
        for (int kc = 0; kc < 2; ++kc) {
            bf16x8 af[4], bfr[4];
            #pragma unroll
            for (int mi = 0; mi < 4; ++mi)
                af[mi] = *(const bf16x8*)&As[(mi * 16 + lm) * PIT + kc * 32 + lk * 8];
            #pragma unroll
            for (int ni = 0; ni < 4; ++ni)
                bfr[ni] = *(const bf16x8*)&Bs[(wn + ni * 16 + lm) * PIT + kc * 32 + lk * 8];
            #pragma unroll
            for (int mi = 0; mi < 4; ++mi)
                #pragma unroll
                for (int ni = 0; ni < 4; ++ni)
                    acc[mi][ni] = __builtin_amdgcn_mfma_f32_16x16x32_bf16(
                        af[mi], bfr[ni], acc[mi][ni], 0, 0, 0);
        }
        __syncthreads();
    }

    // ---- epilogue: bias + ReLU, then LN row stats ----
    // C/D layout: col = wn + ni*16 + lm, row = mi*16 + lk*4 + r
    float* scrS = (float*)As;          // [4 waves][64 rows]
    float* scrQ = scrS + 256;

    float s_[4][4] = {}, q_[4][4] = {};
    #pragma unroll
    for (int ni = 0; ni < 4; ++ni) {
        float bv = bias[wn + ni * 16 + lm];
        #pragma unroll
        for (int mi = 0; mi < 4; ++mi)
            #pragma unroll
            for (int r = 0; r < 4; ++r) {
                float h = fmaxf(acc[mi][ni][r] + bv, 0.f);
                acc[mi][ni][r] = h;
                s_[mi][r] += h;
                q_[mi][r] += h * h;
            }
    }
    #pragma unroll
    for (int off = 1; off < 16; off <<= 1)
        #pragma unroll
        for (int mi = 0; mi < 4; ++mi)
            #pragma unroll
            for (int r = 0; r < 4; ++r) {
                s_[mi][r] += __shfl_xor(s_[mi][r], off, 64);
                q_[mi][r] += __shfl_xor(q_[mi][r], off, 64);
            }
    if (lm == 0) {
        #pragma unroll
        for (int mi = 0; mi < 4; ++mi)
            #pragma unroll
            for (int r = 0; r < 4; ++r) {
                int row = mi * 16 + lk * 4 + r;
                scrS[wave * 64 + row] = s_[mi][r];
                scrQ[wave * 64 + row] = q_[mi][r];
            }
    }
    __syncthreads();

    float mu[4][4], rs[4][4];
    #pragma unroll
    for (int mi = 0; mi < 4; ++mi)
        #pragma unroll
        for (int r = 0; r < 4; ++r) {
            int row = mi * 16 + lk * 4 + r;
            float S = scrS[row] + scrS[64 + row] + scrS[128 + row] + scrS[192 + row];
            float Q = scrQ[row] + scrQ[64 + row] + scrQ[128 + row] + scrQ[192 + row];
            float m_ = S * (1.f / 256.f);
            float v_ = Q * (1.f / 256.f) - m_ * m_;
            mu[mi][r] = m_;
            rs[mi][r] = rsqrtf(v_ + LN_EPS);
        }

    if constexpr (MODE == 0) {
        size_t obase = ((size_t)(bb * SP + s0 + 1)) << 8;
        #pragma unroll
        for (int ni = 0; ni < 4; ++ni) {
            int col = wn + ni * 16 + lm;
            float gv = g[col], bv2 = bt[col];
            #pragma unroll
            for (int mi = 0; mi < 4; ++mi)
                #pragma unroll
                for (int r = 0; r < 4; ++r) {
                    int row = mi * 16 + lk * 4 + r;
                    float o = (acc[mi][ni][r] - mu[mi][r]) * rs[mi][r] * gv + bv2;
                    outB[obase + ((size_t)row << 8) + col] = (__bf16)o;
                }
        }
    } else {
        float p_[4][4] = {};
        #pragma unroll
        for (int ni = 0; ni < 4; ++ni) {
            int col = wn + ni * 16 + lm;
            float gv = g[col], bv2 = bt[col], wv = lw[col];
            #pragma unroll
            for (int mi = 0; mi < 4; ++mi)
                #pragma unroll
                for (int r = 0; r < 4; ++r) {
                    float o = (acc[mi][ni][r] - mu[mi][r]) * rs[mi][r] * gv + bv2;
                    p_[mi][r] += o * wv;
                }
        }
        #pragma unroll
        for (int off = 1; off < 16; off <<= 1)
            #pragma unroll
            for (int mi = 0; mi < 4; ++mi)
                #pragma unroll
                for (int r = 0; r < 4; ++r)
                    p_[mi][r] += __shfl_xor(p_[mi][r], off, 64);
        __syncthreads();   // everyone done reading scrS/scrQ
        if (lm == 0) {
            #pragma unroll
            for (int mi = 0; mi < 4; ++mi)
                #pragma unroll
                for (int r = 0; r < 4; ++r)
                    scrS[wave * 64 + (mi * 16 + lk * 4 + r)] = p_[mi][r];
        }
        __syncthreads();
        if (tid < 64) {
            int row = tid;
            float v = scrS[row] + scrS[64 + row] + scrS[128 + row] + scrS[192 + row]
                      + lb[0];
            if (mask[m0 + row]) v = 0.f;
            outF[m0 + row] = v;
        }
    }
}

// ---------------------------------------------------------------------------
extern "C" void kernel_launch(void* const* d_in, const int* in_sizes, int n_in,
                              void* d_out, int out_size, void* d_ws, size_t ws_size,
                              hipStream_t stream)
{
    const float* x            = (const float*)d_in[0];
    const unsigned char* mask = (const unsigned char*)d_in[1];
    const int* duration       = (const int*)d_in[2];
    const float* w1  = (const float*)d_in[4];
    const float* b1  = (const float*)d_in[5];
    const float* g1  = (const float*)d_in[6];
    const float* be1 = (const float*)d_in[7];
    const float* w2  = (const float*)d_in[8];
    const float* b2  = (const float*)d_in[9];
    const float* g2  = (const float*)d_in[10];
    const float* be2 = (const float*)d_in[11];
    const float* lw  = (const float*)d_in[12];
    const float* lb  = (const float*)d_in[13];

    float* out        = (float*)d_out;
    float* out0       = out;                                  // [B,T,D]
    float* out_logdur = out + (size_t)Bb * TMAX * Dd;         // [B,S]
    float* out_dur    = out_logdur + (size_t)Bb * Ss;         // [B,S]
    float* out_mel    = out_dur + (size_t)Bb * Ss;            // [B]

    char* ws = (char*)d_ws;
    __bf16* xp2  = (__bf16*)ws;                               // 32*1026*256
    __bf16* wTT1 = xp2 + (size_t)Bb * SP * 256;               // 256*768
    __bf16* wTT2 = wTT1 + (size_t)Ff * KK;
    int*    idx  = (int*)(wTT2 + (size_t)Ff * KK);            // 32*8192

    prep_k<<<1584, 256, 0, stream>>>(w1, w2, wTT1, wTT2,
                                     duration, out_dur, out_mel, idx, xp2);
    gemm_fused<0><<<GEMM_BLK + GATH_HALF, 256, 0, stream>>>(
        x, nullptr, wTT1, b1, g1, be1, nullptr, nullptr, nullptr,
        xp2, nullptr, idx, (float4*)out0);
    gemm_fused<1><<<GEMM_BLK + GATH_HALF, 256, 0, stream>>>(
        x, xp2, wTT2, b2, g2, be2, lw, lb, mask,
        nullptr, out_logdur, idx, (float4*)out0);
}

// Round 6
// 356.184 us; speedup vs baseline: 1.0898x; 1.0898x over previous
//
#include <hip/hip_runtime.h>
#include <cstddef>

// Problem constants (fixed by reference setup)
constexpr int Bb   = 32;
constexpr int Ss   = 1024;
constexpr int Dd   = 256;
constexpr int Ff   = 256;
constexpr int TMAX = 8192;
constexpr int MM   = Bb * Ss;          // 32768 rows
constexpr int KK   = 768;              // 3*256 reduction dim
constexpr int SP   = 1026;             // padded seq len (zero rows at 0, 1025)
constexpr float LN_EPS = 1e-5f;
constexpr int PIT  = 72;               // LDS pitch (bf16): 144 B rows
constexpr int OPIT = 264;              // epilogue store-tile pitch (bf16)

constexpr int GEMM_BLK  = MM / 64;                   // 512 gemm blocks/launch
constexpr int RIDER_PER = 2048;                      // rider blocks per launch
constexpr int RIDER_F4  = 4096;                      // float4s per rider block

typedef __bf16 bf16x8 __attribute__((ext_vector_type(8)));
typedef __bf16 bf16x4 __attribute__((ext_vector_type(4)));
typedef float  f32x4  __attribute__((ext_vector_type(4)));

// ---------------------------------------------------------------------------
// prep_k: three fused prep jobs, split by blockIdx.
//   [0,1536):    pack conv weights [F][D][K] fp32 -> [F][K*256+D] bf16
//   [1536,1568): per-batch cumsum + dur->float + mel_len + searchsorted
//   [1568,1584): zero xp2 pad rows (j=0 and j=1025)
// ---------------------------------------------------------------------------
__global__ __launch_bounds__(256) void prep_k(
    const float* __restrict__ w1, const float* __restrict__ w2,
    __bf16* __restrict__ wTT1, __bf16* __restrict__ wTT2,
    const int* __restrict__ dur, float* __restrict__ dur_out,
    float* __restrict__ mel_out, int* __restrict__ idx,
    __bf16* __restrict__ xp2)
{
    __shared__ int ic[1024];
    __shared__ int sc[256];
    const int blk = blockIdx.x;
    const int tid = threadIdx.x;

    if (blk < 1536) {                       // ---- pack weights ----
        int i = blk * 256 + tid;
        const float* w = w1;
        __bf16* o = wTT1;
        int j = i;
        if (j >= Ff * KK) { j -= Ff * KK; w = w2; o = wTT2; }
        int d  = j & 255;
        int fk = j >> 8;                    // f*3 + k
        int f  = fk / 3;
        int k  = fk - f * 3;
        o[(size_t)f * KK + k * 256 + d] = (__bf16)w[((size_t)(f * 256 + d)) * 3 + k];
        return;
    }
    if (blk >= 1568) {                      // ---- zero xp2 pad rows ----
        int j = (blk - 1568) * 256 + tid;   // 0..4095
        int b = j >> 7;
        int r = (j >> 6) & 1;
        int d = (j & 63) * 4;
        *(bf16x4*)&xp2[((size_t)b * SP + (size_t)r * (SP - 1)) * 256 + d] =
            (bf16x4)(__bf16)0.f;
        return;
    }
    // ---- cumsum + searchsorted for batch b ----
    int b = blk - 1536;
    int4 d4 = ((const int4*)(dur + b * 1024))[tid];
    int l0 = d4.x, l1 = l0 + d4.y, l2 = l1 + d4.z, l3 = l2 + d4.w;
    sc[tid] = l3;
    __syncthreads();
    for (int off = 1; off < 256; off <<= 1) {
        int v = (tid >= off) ? sc[tid - off] : 0;
        __syncthreads();
        sc[tid] += v;
        __syncthreads();
    }
    int excl = sc[tid] - l3;
    ((int4*)ic)[tid] = make_int4(excl + l0, excl + l1, excl + l2, excl + l3);
    ((float4*)(dur_out + b * 1024))[tid] =
        make_float4((float)d4.x, (float)d4.y, (float)d4.z, (float)d4.w);
    if (tid == 255) mel_out[b] = (float)min(excl + l3, TMAX);
    __syncthreads();
    int mel = min(ic[1023], TMAX);
    for (int t = tid; t < TMAX; t += 256) {
        int lo = 0, hi = 1024;
        #pragma unroll
        for (int it = 0; it < 10; ++it) {
            int mid = (lo + hi) >> 1;
            if (ic[mid] <= t) lo = mid + 1; else hi = mid;
        }
        idx[b * TMAX + t] = (t < mel) ? min(lo, 1023) : -1;
    }
}

// ---------------------------------------------------------------------------
// Fused conv-as-GEMM + bias + ReLU + LayerNorm [+ linear head], with long
// gather-rider blocks (blockIdx >= GEMM_BLK) overlapping pure-HBM gather work
// with the MFMA/LDS-bound gemm. Each rider block handles 4096 float4s with
// 16 independent loads in flight per thread.
// Tile: BM=64 x BN=256 (full F), 256 threads / 4 waves, 64x64 per wave.
// MODE 0: A = fp32 x converted in staging; LN out bf16 -> padded xp2 via
//         LDS-transposed coalesced stores; gather half #0.
// MODE 1: A = xp2; writes log_dur fp32; gather half #1.
// ---------------------------------------------------------------------------
template<int MODE>
__global__ __launch_bounds__(256, 3) void gemm_fused(
    const float* __restrict__ Xf,    // [32][1024][256] fp32
    const __bf16* __restrict__ Ap,   // [32][1026][256] bf16 padded (MODE 1)
    const __bf16* __restrict__ Bw,   // [256][768]
    const float* __restrict__ bias,
    const float* __restrict__ g, const float* __restrict__ bt,
    const float* __restrict__ lw, const float* __restrict__ lb,
    const unsigned char* __restrict__ mask,
    __bf16* __restrict__ outB, float* __restrict__ outF,
    const int* __restrict__ idx, f32x4* __restrict__ outv)
{
    __shared__ __bf16 As[64 * PIT];    // 9216 B
    __shared__ __bf16 Bs[64 * OPIT];   // 33792 B (k-loop uses 256*PIT=36864.. see union)
    __shared__ __bf16 Bs2[256 * PIT - 64 * OPIT];  // pad union to 36864 B total

    const int tid = threadIdx.x;

    if (blockIdx.x >= GEMM_BLK) {
        // ---- long gather rider: 16 float4 per thread, unrolled for MLP ----
        int rblk = blockIdx.x - GEMM_BLK + MODE * RIDER_PER;
        size_t base = (size_t)rblk * RIDER_F4 + tid;
        int sarr[16];
        #pragma unroll
        for (int it = 0; it < 16; ++it) {
            size_t gg = base + (size_t)it * 256;
            sarr[it] = idx[gg >> 6];
        }
        f32x4 v[16];
        #pragma unroll
        for (int it = 0; it < 16; ++it) {
            size_t gg = base + (size_t)it * 256;
            int row = (int)(gg >> 6);
            int col = (int)(gg & 63);
            v[it] = (f32x4)0.f;
            if (sarr[it] >= 0) {
                int b = row >> 13;
                v[it] = ((const f32x4*)Xf)[((size_t)(b << 10) + sarr[it]) * 64 + col];
            }
        }
        #pragma unroll
        for (int it = 0; it < 16; ++it)
            __builtin_nontemporal_store(v[it], &outv[base + (size_t)it * 256]);
        return;
    }

    const int m0   = blockIdx.x * 64;
    const int bb   = m0 >> 10;
    const int s0   = m0 & 1023;
    const int wave = tid >> 6;
    const int lane = tid & 63;
    const int wn   = wave * 64;
    const int lm   = lane & 15;
    const int lk   = lane >> 4;

    __bf16* BsK = Bs;                  // k-loop view: 256 rows x PIT

    f32x4 acc[4][4] = {};              // [mi][ni]

    for (int step = 0; step < KK / 64; ++step) {
        const int kk0  = step * 64;
        const int kblk = kk0 >> 8;     // conv tap
        const int d0   = kk0 & 255;

        // ---- stage A: 64 rows x 64 bf16 ----
        if constexpr (MODE == 0) {
            #pragma unroll
            for (int i = 0; i < 4; ++i) {
                int c = i * 256 + tid;          // 0..1023
                int r = c >> 4, q = c & 15;     // r:0..63, q:0..15
                int sg = s0 + r + kblk - 1;
                bf16x4 o = (bf16x4)(__bf16)0.f;
                if ((unsigned)sg < 1024u) {
                    float4 v = *(const float4*)&Xf[
                        (((size_t)(bb << 10) + sg) << 8) + d0 + q * 4];
                    o[0] = (__bf16)v.x; o[1] = (__bf16)v.y;
                    o[2] = (__bf16)v.z; o[3] = (__bf16)v.w;
                }
                *(bf16x4*)&As[r * PIT + q * 4] = o;
            }
        } else {
            const __bf16* aSrc = Ap + (((size_t)(bb * SP + s0 + kblk)) << 8) + d0;
            #pragma unroll
            for (int i = 0; i < 2; ++i) {
                int c = i * 256 + tid, r = c >> 3, q = c & 7;
                *(bf16x8*)&As[r * PIT + q * 8] =
                    *(const bf16x8*)&aSrc[((size_t)r << 8) + q * 8];
            }
        }
        // ---- stage B: 256 rows x 64 bf16 ----
        const __bf16* bSrc = Bw + kk0;
        #pragma unroll
        for (int i = 0; i < 8; ++i) {
            int c = i * 256 + tid, r = c >> 3, q = c & 7;
            *(bf16x8*)&BsK[r * PIT + q * 8] =
                *(const bf16x8*)&bSrc[(size_t)r * KK + q * 8];
        }
        __syncthreads();
        #pragma unroll
        for (int kc = 0; kc < 2; ++kc) {
            bf16x8 af[4], bfr[4];
            #pragma unroll
            for (int mi = 0; mi < 4; ++mi)
                af[mi] = *(const bf16x8*)&As[(mi * 16 + lm) * PIT + kc * 32 + lk * 8];
            #pragma unroll
            for (int ni = 0; ni < 4; ++ni)
                bfr[ni] = *(const bf16x8*)&BsK[(wn + ni * 16 + lm) * PIT + kc * 32 + lk * 8];
            #pragma unroll
            for (int mi = 0; mi < 4; ++mi)
                #pragma unroll
                for (int ni = 0; ni < 4; ++ni)
                    acc[mi][ni] = __builtin_amdgcn_mfma_f32_16x16x32_bf16(
                        af[mi], bfr[ni], acc[mi][ni], 0, 0, 0);
        }
        __syncthreads();
    }

    // ---- epilogue: bias + ReLU, then LN row stats ----
    // C/D layout: col = wn + ni*16 + lm, row = mi*16 + lk*4 + r
    float* scrS = (float*)As;          // [4 waves][64 rows]
    float* scrQ = scrS + 256;

    float s_[4][4] = {}, q_[4][4] = {};
    #pragma unroll
    for (int ni = 0; ni < 4; ++ni) {
        float bv = bias[wn + ni * 16 + lm];
        #pragma unroll
        for (int mi = 0; mi < 4; ++mi)
            #pragma unroll
            for (int r = 0; r < 4; ++r) {
                float h = fmaxf(acc[mi][ni][r] + bv, 0.f);
                acc[mi][ni][r] = h;
                s_[mi][r] += h;
                q_[mi][r] += h * h;
            }
    }
    #pragma unroll
    for (int off = 1; off < 16; off <<= 1)
        #pragma unroll
        for (int mi = 0; mi < 4; ++mi)
            #pragma unroll
            for (int r = 0; r < 4; ++r) {
                s_[mi][r] += __shfl_xor(s_[mi][r], off, 64);
                q_[mi][r] += __shfl_xor(q_[mi][r], off, 64);
            }
    if (lm == 0) {
        #pragma unroll
        for (int mi = 0; mi < 4; ++mi)
            #pragma unroll
            for (int r = 0; r < 4; ++r) {
                int row = mi * 16 + lk * 4 + r;
                scrS[wave * 64 + row] = s_[mi][r];
                scrQ[wave * 64 + row] = q_[mi][r];
            }
    }
    __syncthreads();

    float mu[4][4], rs[4][4];
    #pragma unroll
    for (int mi = 0; mi < 4; ++mi)
        #pragma unroll
        for (int r = 0; r < 4; ++r) {
            int row = mi * 16 + lk * 4 + r;
            float S = scrS[row] + scrS[64 + row] + scrS[128 + row] + scrS[192 + row];
            float Q = scrQ[row] + scrQ[64 + row] + scrQ[128 + row] + scrQ[192 + row];
            float m_ = S * (1.f / 256.f);
            float v_ = Q * (1.f / 256.f) - m_ * m_;
            mu[mi][r] = m_;
            rs[mi][r] = rsqrtf(v_ + LN_EPS);
        }

    if constexpr (MODE == 0) {
        // ---- LDS-transposed coalesced store of the 64x256 bf16 LN tile ----
        __bf16* tile = Bs;             // 64 rows x OPIT
        #pragma unroll
        for (int ni = 0; ni < 4; ++ni) {
            int col = wn + ni * 16 + lm;
            float gv = g[col], bv2 = bt[col];
            #pragma unroll
            for (int mi = 0; mi < 4; ++mi)
                #pragma unroll
                for (int r = 0; r < 4; ++r) {
                    int row = mi * 16 + lk * 4 + r;
                    float o = (acc[mi][ni][r] - mu[mi][r]) * rs[mi][r] * gv + bv2;
                    tile[row * OPIT + col] = (__bf16)o;
                }
        }
        __syncthreads();
        size_t obase = ((size_t)(bb * SP + s0 + 1)) << 8;
        #pragma unroll
        for (int i = 0; i < 8; ++i) {
            int c = i * 256 + tid;     // 0..2047
            int row = c >> 5, q = c & 31;
            *(bf16x8*)&outB[obase + ((size_t)row << 8) + q * 8] =
                *(bf16x8*)&tile[row * OPIT + q * 8];
        }
    } else {
        float p_[4][4] = {};
        #pragma unroll
        for (int ni = 0; ni < 4; ++ni) {
            int col = wn + ni * 16 + lm;
            float gv = g[col], bv2 = bt[col], wv = lw[col];
            #pragma unroll
            for (int mi = 0; mi < 4; ++mi)
                #pragma unroll
                for (int r = 0; r < 4; ++r) {
                    float o = (acc[mi][ni][r] - mu[mi][r]) * rs[mi][r] * gv + bv2;
                    p_[mi][r] += o * wv;
                }
        }
        #pragma unroll
        for (int off = 1; off < 16; off <<= 1)
            #pragma unroll
            for (int mi = 0; mi < 4; ++mi)
                #pragma unroll
                for (int r = 0; r < 4; ++r)
                    p_[mi][r] += __shfl_xor(p_[mi][r], off, 64);
        __syncthreads();   // everyone done reading scrS/scrQ
        if (lm == 0) {
            #pragma unroll
            for (int mi = 0; mi < 4; ++mi)
                #pragma unroll
                for (int r = 0; r < 4; ++r)
                    scrS[wave * 64 + (mi * 16 + lk * 4 + r)] = p_[mi][r];
        }
        __syncthreads();
        if (tid < 64) {
            int row = tid;
            float v = scrS[row] + scrS[64 + row] + scrS[128 + row] + scrS[192 + row]
                      + lb[0];
            if (mask[m0 + row]) v = 0.f;
            outF[m0 + row] = v;
        }
    }
}

// ---------------------------------------------------------------------------
extern "C" void kernel_launch(void* const* d_in, const int* in_sizes, int n_in,
                              void* d_out, int out_size, void* d_ws, size_t ws_size,
                              hipStream_t stream)
{
    const float* x            = (const float*)d_in[0];
    const unsigned char* mask = (const unsigned char*)d_in[1];
    const int* duration       = (const int*)d_in[2];
    const float* w1  = (const float*)d_in[4];
    const float* b1  = (const float*)d_in[5];
    const float* g1  = (const float*)d_in[6];
    const float* be1 = (const float*)d_in[7];
    const float* w2  = (const float*)d_in[8];
    const float* b2  = (const float*)d_in[9];
    const float* g2  = (const float*)d_in[10];
    const float* be2 = (const float*)d_in[11];
    const float* lw  = (const float*)d_in[12];
    const float* lb  = (const float*)d_in[13];

    float* out        = (float*)d_out;
    float* out0       = out;                                  // [B,T,D]
    float* out_logdur = out + (size_t)Bb * TMAX * Dd;         // [B,S]
    float* out_dur    = out_logdur + (size_t)Bb * Ss;         // [B,S]
    float* out_mel    = out_dur + (size_t)Bb * Ss;            // [B]

    char* ws = (char*)d_ws;
    __bf16* xp2  = (__bf16*)ws;                               // 32*1026*256
    __bf16* wTT1 = xp2 + (size_t)Bb * SP * 256;               // 256*768
    __bf16* wTT2 = wTT1 + (size_t)Ff * KK;
    int*    idx  = (int*)(wTT2 + (size_t)Ff * KK);            // 32*8192

    prep_k<<<1584, 256, 0, stream>>>(w1, w2, wTT1, wTT2,
                                     duration, out_dur, out_mel, idx, xp2);
    gemm_fused<0><<<GEMM_BLK + RIDER_PER, 256, 0, stream>>>(
        x, nullptr, wTT1, b1, g1, be1, nullptr, nullptr, nullptr,
        xp2, nullptr, idx, (f32x4*)out0);
    gemm_fused<1><<<GEMM_BLK + RIDER_PER, 256, 0, stream>>>(
        x, xp2, wTT2, b2, g2, be2, lw, lb, mask,
        nullptr, out_logdur, idx, (f32x4*)out0);
}

// Round 7
// 338.364 us; speedup vs baseline: 1.1472x; 1.0527x over previous
//
#include <hip/hip_runtime.h>
#include <cstddef>

// Problem constants (fixed by reference setup)
constexpr int Bb   = 32;
constexpr int Ss   = 1024;
constexpr int Dd   = 256;
constexpr int Ff   = 256;
constexpr int TMAX = 8192;
constexpr int MM   = Bb * Ss;          // 32768 rows
constexpr int KK   = 768;              // 3*256 reduction dim
constexpr int SP   = 1026;             // padded seq len (zero rows at 0, 1025)
constexpr float LN_EPS = 1e-5f;
constexpr int OPIT = 264;              // epilogue store-tile pitch (bf16)

constexpr int GEMM_BLK  = MM / 64;     // 512 gemm blocks/launch
constexpr int RIDER_PER = 2048;        // rider blocks per launch
constexpr int RIDER_F4  = 4096;        // float4s per rider block

// prep_k block ranges
constexpr int PREP_W   = 1536;                 // weight pack+swizzle
constexpr int PREP_X   = Bb * SP * 64 / 256;   // 8208: x -> xp1 bf16 padded
constexpr int PREP_CUM = Bb;                   // 32: cumsum+searchsorted
constexpr int PREP_PAD = 16;                   // zero xp2 pad rows
constexpr int PREP_TOT = PREP_W + PREP_X + PREP_CUM + PREP_PAD;

typedef __bf16 bf16x8 __attribute__((ext_vector_type(8)));
typedef __bf16 bf16x4 __attribute__((ext_vector_type(4)));
typedef float  f32x4  __attribute__((ext_vector_type(4)));

// async global->LDS DMA, 16 B per lane; LDS dest = wave-uniform base + lane*16
#define GLOAD_LDS16(gp, lp)                                                     \
    __builtin_amdgcn_global_load_lds(                                           \
        (const __attribute__((address_space(1))) void*)(gp),                    \
        (__attribute__((address_space(3))) void*)(lp), 16, 0, 0)

// ---------------------------------------------------------------------------
// prep_k: four fused prep jobs, split by blockIdx.
//   [0,1536):  pack conv weights [F][D][K] fp32 -> step-major XOR-swizzled
//              bf16 wTTs[12][256 r][8 cph][8 e]; physical chunk cph holds
//              logical chunk cph^(r&7) of the 64-wide k-slice of step.
//   [.., +8208): pack x fp32 -> xp1 bf16 [32][1026][256], zero rows 0/1025
//   [.., +32):   per-batch cumsum + dur->float + mel_len + searchsorted
//   [.., +16):   zero xp2 pad rows
// ---------------------------------------------------------------------------
__global__ __launch_bounds__(256) void prep_k(
    const float* __restrict__ w1, const float* __restrict__ w2,
    __bf16* __restrict__ wTTs1, __bf16* __restrict__ wTTs2,
    const float* __restrict__ x, __bf16* __restrict__ xp1,
    const int* __restrict__ dur, float* __restrict__ dur_out,
    float* __restrict__ mel_out, int* __restrict__ idx,
    __bf16* __restrict__ xp2)
{
    __shared__ int ic[1024];
    __shared__ int sc[256];
    const int blk = blockIdx.x;
    const int tid = threadIdx.x;

    if (blk < PREP_W) {                     // ---- pack + swizzle weights ----
        int i = blk * 256 + tid;
        const float* w = w1;
        __bf16* o = wTTs1;
        int j = i;
        if (j >= Ff * KK) { j -= Ff * KK; w = w2; o = wTTs2; }
        int e   = j & 7;
        int cph = (j >> 3) & 7;
        int r   = (j >> 6) & 255;           // output feature f
        int st  = j >> 14;                  // k-step 0..11
        int clog = cph ^ (r & 7);
        int kk  = st * 64 + clog * 8 + e;   // logical k index 0..767
        int k   = kk >> 8, d = kk & 255;
        o[j] = (__bf16)w[((size_t)(r * 256 + d)) * 3 + k];
        return;
    }
    if (blk < PREP_W + PREP_X) {            // ---- pack x -> xp1 ----
        int i   = (blk - PREP_W) * 256 + tid;
        int row = i >> 6;
        int d4  = (i & 63) * 4;
        int b   = row / SP;
        int j   = row - b * SP;
        bf16x4 o = (bf16x4)(__bf16)0.f;
        if (j != 0 && j != SP - 1) {
            float4 v = *(const float4*)&x[(((size_t)(b << 10) + (j - 1)) << 8) + d4];
            o[0] = (__bf16)v.x; o[1] = (__bf16)v.y;
            o[2] = (__bf16)v.z; o[3] = (__bf16)v.w;
        }
        *(bf16x4*)&xp1[((size_t)row << 8) + d4] = o;
        return;
    }
    if (blk >= PREP_W + PREP_X + PREP_CUM) {    // ---- zero xp2 pad rows ----
        int j = (blk - (PREP_W + PREP_X + PREP_CUM)) * 256 + tid;  // 0..4095
        int b = j >> 7;
        int r = (j >> 6) & 1;
        int d = (j & 63) * 4;
        *(bf16x4*)&xp2[((size_t)b * SP + (size_t)r * (SP - 1)) * 256 + d] =
            (bf16x4)(__bf16)0.f;
        return;
    }
    // ---- cumsum + searchsorted for batch b ----
    int b = blk - (PREP_W + PREP_X);
    int4 d4 = ((const int4*)(dur + b * 1024))[tid];
    int l0 = d4.x, l1 = l0 + d4.y, l2 = l1 + d4.z, l3 = l2 + d4.w;
    sc[tid] = l3;
    __syncthreads();
    for (int off = 1; off < 256; off <<= 1) {
        int v = (tid >= off) ? sc[tid - off] : 0;
        __syncthreads();
        sc[tid] += v;
        __syncthreads();
    }
    int excl = sc[tid] - l3;
    ((int4*)ic)[tid] = make_int4(excl + l0, excl + l1, excl + l2, excl + l3);
    ((float4*)(dur_out + b * 1024))[tid] =
        make_float4((float)d4.x, (float)d4.y, (float)d4.z, (float)d4.w);
    if (tid == 255) mel_out[b] = (float)min(excl + l3, TMAX);
    __syncthreads();
    int mel = min(ic[1023], TMAX);
    for (int t = tid; t < TMAX; t += 256) {
        int lo = 0, hi = 1024;
        #pragma unroll
        for (int it = 0; it < 10; ++it) {
            int mid = (lo + hi) >> 1;
            if (ic[mid] <= t) lo = mid + 1; else hi = mid;
        }
        idx[b * TMAX + t] = (t < mel) ? min(lo, 1023) : -1;
    }
}

// ---------------------------------------------------------------------------
// Fused conv-as-GEMM + bias + ReLU + LayerNorm [+ linear head] with
// global_load_lds DMA staging into an XOR-swizzled LDS layout, plus long
// gather-rider blocks (blockIdx >= GEMM_BLK) overlapping pure-HBM gather.
// LDS layout (A and B): row-pitch 64 bf16 (128 B); 16B-chunk at physical
// position c holds logical chunk c ^ (row&7)  -> DMA-linear AND b128 reads
// stay at the 8-lane/bank-group floor.
// Tile: BM=64 x BN=256 (full F), 256 threads / 4 waves, 64x64 per wave.
// MODE 0: LN out bf16 -> padded xp2 (coalesced via LDS tile); riders half 0.
// MODE 1: log_dur fp32; riders half 1.
// ---------------------------------------------------------------------------
template<int MODE>
__global__ __launch_bounds__(256, 3) void gemm_fused(
    const float* __restrict__ Xf,    // [32][1024][256] fp32 (riders only)
    const __bf16* __restrict__ Ap,   // [32][1026][256] bf16 padded
    const __bf16* __restrict__ BwS,  // [12][256][64] step-major swizzled
    const float* __restrict__ bias,
    const float* __restrict__ g, const float* __restrict__ bt,
    const float* __restrict__ lw, const float* __restrict__ lb,
    const unsigned char* __restrict__ mask,
    __bf16* __restrict__ outB, float* __restrict__ outF,
    const int* __restrict__ idx, f32x4* __restrict__ outv)
{
    __shared__ __bf16 SMEM[64 * 64 + 256 * 64 + 1088];   // 43136 B
    __bf16* As = SMEM;               // 4096 elems (A tile / LN scratch)
    __bf16* Bs = SMEM + 4096;        // 16384 elems (B tile / store tile)

    const int tid = threadIdx.x;

    if (blockIdx.x >= GEMM_BLK) {
        // ---- long gather rider: 16 float4 per thread, deep MLP ----
        int rblk = blockIdx.x - GEMM_BLK + MODE * RIDER_PER;
        size_t base = (size_t)rblk * RIDER_F4 + tid;
        int sarr[16];
        #pragma unroll
        for (int it = 0; it < 16; ++it) {
            size_t gg = base + (size_t)it * 256;
            sarr[it] = idx[gg >> 6];
        }
        f32x4 v[16];
        #pragma unroll
        for (int it = 0; it < 16; ++it) {
            size_t gg = base + (size_t)it * 256;
            int row = (int)(gg >> 6);
            int col = (int)(gg & 63);
            v[it] = (f32x4)0.f;
            if (sarr[it] >= 0) {
                int b = row >> 13;
                v[it] = ((const f32x4*)Xf)[((size_t)(b << 10) + sarr[it]) * 64 + col];
            }
        }
        #pragma unroll
        for (int it = 0; it < 16; ++it)
            __builtin_nontemporal_store(v[it], &outv[base + (size_t)it * 256]);
        return;
    }

    const int m0   = blockIdx.x * 64;
    const int bb   = m0 >> 10;
    const int s0   = m0 & 1023;
    const int wave = tid >> 6;
    const int lane = tid & 63;
    const int wn   = wave * 64;
    const int lm   = lane & 15;
    const int lk   = lane >> 4;
    const int l3   = lane & 7;
    const int lr   = lane >> 3;          // 0..7

    // per-lane A global offset within an 8-row group (elements):
    // row lr, logical chunk (l3 ^ lr) -> lands at physical chunk l3 = lane dest
    const int aLaneOff = lr * 256 + ((l3 ^ lr) << 3);
    // fragment physical chunk for kc=0 (kc=1 -> ^4)
    const int ch0 = lk ^ (lm & 7);

    f32x4 acc[4][4] = {};                // [mi][ni]

    const size_t aRowBase = ((size_t)(bb * SP + s0)) << 8;

    for (int step = 0; step < 12; ++step) {
        const int kk0  = step * 64;
        const int kblk = kk0 >> 8;       // conv tap 0..2
        const int d0   = kk0 & 255;

        // ---- stage A: 64 rows x 64 bf16, 8 groups of 8 rows, DMA ----
        const __bf16* aSrc = Ap + aRowBase + ((size_t)kblk << 8) + d0 + aLaneOff;
        #pragma unroll
        for (int i = 0; i < 2; ++i) {
            int grp = wave * 2 + i;
            GLOAD_LDS16(aSrc + (size_t)grp * 2048, As + grp * 512);
        }
        // ---- stage B: 256 rows x 64 bf16, 32 groups, fully linear DMA ----
        const __bf16* bSrc = BwS + (size_t)step * 16384 + lane * 8;
        #pragma unroll
        for (int i = 0; i < 8; ++i) {
            int grp = wave * 8 + i;
            GLOAD_LDS16(bSrc + (size_t)grp * 512, Bs + grp * 512);
        }
        __syncthreads();

        #pragma unroll
        for (int kc = 0; kc < 2; ++kc) {
            const int ch = ch0 ^ (kc << 2);
            bf16x8 af[4], bfr[4];
            #pragma unroll
            for (int mi = 0; mi < 4; ++mi)
                af[mi] = *(const bf16x8*)&As[(mi * 16 + lm) * 64 + ch * 8];
            #pragma unroll
            for (int ni = 0; ni < 4; ++ni)
                bfr[ni] = *(const bf16x8*)&Bs[(wn + ni * 16 + lm) * 64 + ch * 8];
            #pragma unroll
            for (int mi = 0; mi < 4; ++mi)
                #pragma unroll
                for (int ni = 0; ni < 4; ++ni)
                    acc[mi][ni] = __builtin_amdgcn_mfma_f32_16x16x32_bf16(
                        af[mi], bfr[ni], acc[mi][ni], 0, 0, 0);
        }
        __syncthreads();
    }

    // ---- epilogue: bias + ReLU, then LN row stats ----
    // C/D layout: col = wn + ni*16 + lm, row = mi*16 + lk*4 + r
    float* scrS = (float*)As;            // [4 waves][64 rows]
    float* scrQ = scrS + 256;

    float s_[4][4] = {}, q_[4][4] = {};
    #pragma unroll
    for (int ni = 0; ni < 4; ++ni) {
        float bv = bias[wn + ni * 16 + lm];
        #pragma unroll
        for (int mi = 0; mi < 4; ++mi)
            #pragma unroll
            for (int r = 0; r < 4; ++r) {
                float h = fmaxf(acc[mi][ni][r] + bv, 0.f);
                acc[mi][ni][r] = h;
                s_[mi][r] += h;
                q_[mi][r] += h * h;
            }
    }
    #pragma unroll
    for (int off = 1; off < 16; off <<= 1)
        #pragma unroll
        for (int mi = 0; mi < 4; ++mi)
            #pragma unroll
            for (int r = 0; r < 4; ++r) {
                s_[mi][r] += __shfl_xor(s_[mi][r], off, 64);
                q_[mi][r] += __shfl_xor(q_[mi][r], off, 64);
            }
    if (lm == 0) {
        #pragma unroll
        for (int mi = 0; mi < 4; ++mi)
            #pragma unroll
            for (int r = 0; r < 4; ++r) {
                int row = mi * 16 + lk * 4 + r;
                scrS[wave * 64 + row] = s_[mi][r];
                scrQ[wave * 64 + row] = q_[mi][r];
            }
    }
    __syncthreads();

    float mu[4][4], rs[4][4];
    #pragma unroll
    for (int mi = 0; mi < 4; ++mi)
        #pragma unroll
        for (int r = 0; r < 4; ++r) {
            int row = mi * 16 + lk * 4 + r;
            float S = scrS[row] + scrS[64 + row] + scrS[128 + row] + scrS[192 + row];
            float Q = scrQ[row] + scrQ[64 + row] + scrQ[128 + row] + scrQ[192 + row];
            float m_ = S * (1.f / 256.f);
            float v_ = Q * (1.f / 256.f) - m_ * m_;
            mu[mi][r] = m_;
            rs[mi][r] = rsqrtf(v_ + LN_EPS);
        }

    if constexpr (MODE == 0) {
        // ---- LDS-transposed coalesced store of the 64x256 bf16 LN tile ----
        __bf16* tile = Bs;               // 64 rows x OPIT (fits Bs + tail)
        #pragma unroll
        for (int ni = 0; ni < 4; ++ni) {
            int col = wn + ni * 16 + lm;
            float gv = g[col], bv2 = bt[col];
            #pragma unroll
            for (int mi = 0; mi < 4; ++mi)
                #pragma unroll
                for (int r = 0; r < 4; ++r) {
                    int row = mi * 16 + lk * 4 + r;
                    float o = (acc[mi][ni][r] - mu[mi][r]) * rs[mi][r] * gv + bv2;
                    tile[row * OPIT + col] = (__bf16)o;
                }
        }
        __syncthreads();
        size_t obase = ((size_t)(bb * SP + s0 + 1)) << 8;
        #pragma unroll
        for (int i = 0; i < 8; ++i) {
            int c = i * 256 + tid;       // 0..2047
            int row = c >> 5, q = c & 31;
            *(bf16x8*)&outB[obase + ((size_t)row << 8) + q * 8] =
                *(bf16x8*)&tile[row * OPIT + q * 8];
        }
    } else {
        float p_[4][4] = {};
        #pragma unroll
        for (int ni = 0; ni < 4; ++ni) {
            int col = wn + ni * 16 + lm;
            float gv = g[col], bv2 = bt[col], wv = lw[col];
            #pragma unroll
            for (int mi = 0; mi < 4; ++mi)
                #pragma unroll
                for (int r = 0; r < 4; ++r) {
                    float o = (acc[mi][ni][r] - mu[mi][r]) * rs[mi][r] * gv + bv2;
                    p_[mi][r] += o * wv;
                }
        }
        #pragma unroll
        for (int off = 1; off < 16; off <<= 1)
            #pragma unroll
            for (int mi = 0; mi < 4; ++mi)
                #pragma unroll
                for (int r = 0; r < 4; ++r)
                    p_[mi][r] += __shfl_xor(p_[mi][r], off, 64);
        __syncthreads();                 // done reading scrS/scrQ
        if (lm == 0) {
            #pragma unroll
            for (int mi = 0; mi < 4; ++mi)
                #pragma unroll
                for (int r = 0; r < 4; ++r)
                    scrS[wave * 64 + (mi * 16 + lk * 4 + r)] = p_[mi][r];
        }
        __syncthreads();
        if (tid < 64) {
            int row = tid;
            float v = scrS[row] + scrS[64 + row] + scrS[128 + row] + scrS[192 + row]
                      + lb[0];
            if (mask[m0 + row]) v = 0.f;
            outF[m0 + row] = v;
        }
    }
}

// ---------------------------------------------------------------------------
extern "C" void kernel_launch(void* const* d_in, const int* in_sizes, int n_in,
                              void* d_out, int out_size, void* d_ws, size_t ws_size,
                              hipStream_t stream)
{
    const float* x            = (const float*)d_in[0];
    const unsigned char* mask = (const unsigned char*)d_in[1];
    const int* duration       = (const int*)d_in[2];
    const float* w1  = (const float*)d_in[4];
    const float* b1  = (const float*)d_in[5];
    const float* g1  = (const float*)d_in[6];
    const float* be1 = (const float*)d_in[7];
    const float* w2  = (const float*)d_in[8];
    const float* b2  = (const float*)d_in[9];
    const float* g2  = (const float*)d_in[10];
    const float* be2 = (const float*)d_in[11];
    const float* lw  = (const float*)d_in[12];
    const float* lb  = (const float*)d_in[13];

    float* out        = (float*)d_out;
    float* out0       = out;                                  // [B,T,D]
    float* out_logdur = out + (size_t)Bb * TMAX * Dd;         // [B,S]
    float* out_dur    = out_logdur + (size_t)Bb * Ss;         // [B,S]
    float* out_mel    = out_dur + (size_t)Bb * Ss;            // [B]

    char* ws = (char*)d_ws;
    __bf16* xp1   = (__bf16*)ws;                              // 32*1026*256
    __bf16* xp2   = xp1 + (size_t)Bb * SP * 256;
    __bf16* wTTs1 = xp2 + (size_t)Bb * SP * 256;              // 12*256*64
    __bf16* wTTs2 = wTTs1 + (size_t)Ff * KK;
    int*    idx   = (int*)(wTTs2 + (size_t)Ff * KK);          // 32*8192

    prep_k<<<PREP_TOT, 256, 0, stream>>>(w1, w2, wTTs1, wTTs2, x, xp1,
                                         duration, out_dur, out_mel, idx, xp2);
    gemm_fused<0><<<GEMM_BLK + RIDER_PER, 256, 0, stream>>>(
        x, xp1, wTTs1, b1, g1, be1, nullptr, nullptr, nullptr,
        xp2, nullptr, idx, (f32x4*)out0);
    gemm_fused<1><<<GEMM_BLK + RIDER_PER, 256, 0, stream>>>(
        x, xp2, wTTs2, b2, g2, be2, lw, lb, mask,
        nullptr, out_logdur, idx, (f32x4*)out0);
}